// Round 10
// baseline (742.011 us; speedup 1.0000x reference)
//
#include <hip/hip_runtime.h>
#include <math.h>

// Problem constants: B=8, N=1024, FIN=FOUT=512, H=8, HD=64, BH=64

typedef __attribute__((ext_vector_type(8))) short short8;    // 8 bf16 (4 VGPRs)
typedef __attribute__((ext_vector_type(4))) float floatx4;   // MFMA C/D

// Workspace byte offsets (~89 MB).
// Overlays: VT overlays XT (dead after proj); QLV/KLV overlay VRAW (vtrans
// runs BEFORE quant2); PS overlays QRAW (dead after quant2).
#define OB_WPT   0ull           // 3145728   Wp^T fp32 [k=512][o=1536]
#define OB_XT    3145728ull     // 33554432  x^T fp32 [k=512][t=8192]
#define OB_VT    OB_XT          // 8388608   v^T bf16 (overlay, after proj)
#define OB_QRAW  36700160ull    // 16777216  q raw fp32 (b,h,n,d)
#define OB_PS    OB_QRAW        // 2097152   partial (m,l) x4 (overlay)
#define OB_KRAW  53477376ull    // 16777216  k raw fp32
#define OB_VRAW  70254592ull    // 16777216  v raw fp32
#define OB_QLV   70254592ull    // 8388608   q levels bf16 (overlay vraw lo)
#define OB_KLV   78643200ull    // 8388608   k levels bf16 (overlay vraw hi)
#define OB_RS    87031808ull    // 524288    rowstats float2
#define OB_BM    87556096ull    // 1048576   adj bitmask u64
#define OB_AMAX  88604672ull    // 16        amax_q, amax_k, amax_attn

__device__ __forceinline__ unsigned short bf16_rne(float f) {
    unsigned int u = __float_as_uint(f);
    unsigned int r = u + 0x7fffu + ((u >> 16) & 1u);
    return (unsigned short)(r >> 16);
}
__device__ __forceinline__ float bf16_to_f(unsigned short h) {
    return __uint_as_float(((unsigned int)h) << 16);
}
// exact for values already representable in bf16 (integer levels |x|<=127)
__device__ __forceinline__ unsigned short bf16_exact(float f) {
    return (unsigned short)(__float_as_uint(f) >> 16);
}

// async global->LDS, 16 B per lane; dest = wave-uniform base + lane*16
__device__ __forceinline__ void dma16(const float* g, float* l) {
    __builtin_amdgcn_global_load_lds(
        (__attribute__((address_space(1))) void*)(void*)g,
        (__attribute__((address_space(3))) void*)(void*)l, 16, 0, 0);
}

__device__ __forceinline__ void outer4(float (&acc)[4][4], float4 a, float4 b) {
    float av[4] = {a.x, a.y, a.z, a.w};
    float bv[4] = {b.x, b.y, b.z, b.w};
#pragma unroll
    for (int i = 0; i < 4; ++i)
#pragma unroll
        for (int j = 0; j < 4; ++j)
            acc[i][j] = fmaf(av[i], bv[j], acc[i][j]);
}

// ---------------------------------------------------------------------------
// K0: adjacency (8,1024,1024) i32 -> bitmask (8,1024,16) u64. One word/wave.
// ---------------------------------------------------------------------------
__global__ __launch_bounds__(256) void adj_bits_k(
    const int* __restrict__ adj, unsigned long long* __restrict__ bm)
{
    int tid = threadIdx.x;
    int wv = tid >> 6, lane = tid & 63;
    size_t word = (size_t)blockIdx.x * 4 + wv;       // 131072 words total
    int a = adj[word * 64 + lane];
    unsigned long long m = __ballot(a != 0);
    if (lane == 0) bm[word] = m;
}

// ---------------------------------------------------------------------------
// K0b: fp32 transpose dst[c][r] = src[r][c]; 64x64 LDS tiles, coalesced both
// sides. Pure data movement (bit-exact). grid (C/64, R/64).
// ---------------------------------------------------------------------------
__global__ __launch_bounds__(256) void transp_k(
    const float* __restrict__ src, float* __restrict__ dst, int R, int C)
{
    __shared__ float ls[64][65];
    int tid = threadIdx.x;
    int ct = blockIdx.x, rt = blockIdx.y;
#pragma unroll
    for (int l = 0; l < 4; ++l) {
        int idx = l * 256 + tid;
        int r = idx >> 4, c4 = idx & 15;
        float4 v = *(const float4*)(src + (size_t)(rt * 64 + r) * C + ct * 64 + c4 * 4);
        ls[r][c4 * 4 + 0] = v.x; ls[r][c4 * 4 + 1] = v.y;
        ls[r][c4 * 4 + 2] = v.z; ls[r][c4 * 4 + 3] = v.w;
    }
    __syncthreads();
#pragma unroll
    for (int l = 0; l < 4; ++l) {
        int idx = l * 256 + tid;
        int c = idx >> 4, r4 = idx & 15;
        float4 o = make_float4(ls[r4 * 4 + 0][c], ls[r4 * 4 + 1][c],
                               ls[r4 * 4 + 2][c], ls[r4 * 4 + 3][c]);
        *(float4*)(dst + (size_t)(ct * 64 + c) * R + rt * 64 + r4 * 4) = o;
    }
}

// ---------------------------------------------------------------------------
// K1: all three DoRA-merged weights, written TRANSPOSED: WpT[k][mtx*512+o].
// Scattered dword writes (~3 MB) — cheap; enables DMA staging in the GEMM.
// Per-row numerics identical to all passing rounds.
// ---------------------------------------------------------------------------
__global__ __launch_bounds__(256) void build_wp3_k(
    const float* __restrict__ W_q, const float* __restrict__ A_q,
    const float* __restrict__ B_q, const float* __restrict__ m_q,
    const float* __restrict__ W_k, const float* __restrict__ A_k,
    const float* __restrict__ B_k, const float* __restrict__ m_k,
    const float* __restrict__ W_v, const float* __restrict__ A_v,
    const float* __restrict__ B_v, const float* __restrict__ m_v,
    float* __restrict__ wpT)
{
    __shared__ float brow[16];
    __shared__ __align__(16) float wd[512];
    __shared__ float red[5];
    int o = blockIdx.x;
    int mtx = blockIdx.y;
    const float* W   = mtx == 0 ? W_q : (mtx == 1 ? W_k : W_v);
    const float* A   = mtx == 0 ? A_q : (mtx == 1 ? A_k : A_v);
    const float* Bm  = mtx == 0 ? B_q : (mtx == 1 ? B_k : B_v);
    const float* mag = mtx == 0 ? m_q : (mtx == 1 ? m_k : m_v);
    int ocol = mtx * 512 + o;
    int tid = threadIdx.x;
    if (tid < 16) brow[tid] = Bm[o * 16 + tid];
    __syncthreads();
    float ss = 0.f;
    for (int i = tid; i < 512; i += 256) {
        float acc = W[o * 512 + i];
#pragma unroll
        for (int r = 0; r < 16; ++r) acc = fmaf(brow[r], A[r * 512 + i], acc);
        wd[i] = acc;
        ss = fmaf(acc, acc, ss);
    }
#pragma unroll
    for (int off = 32; off > 0; off >>= 1) ss += __shfl_down(ss, off);
    int lane = tid & 63, wv = tid >> 6;
    if (lane == 0) red[wv] = ss;
    __syncthreads();
    if (tid == 0) red[4] = mag[o] / sqrtf(red[0] + red[1] + red[2] + red[3]);
    __syncthreads();
    float scl = red[4];
    for (int i = tid; i < 512; i += 256)
        wpT[(size_t)i * 1536 + ocol] = wd[i] * scl;
}

// ---------------------------------------------------------------------------
// K2: FUSED fp32 projection via DMA-staged, double-buffered LDS.
// xT[k][t], WpT[k][o] tiles land in LDS in-place via global_load_lds (16B) —
// zero staging VGPRs / ds_writes. Inner loop and per-element k-order are
// IDENTICAL to round 3/5/7/9 -> bit-identical q/k/v raw values and amax.
// grid (128 t-tiles, 24 o-tiles): o tiles 0-7 q, 8-15 k, 16-23 v.
// ---------------------------------------------------------------------------
__global__ __launch_bounds__(256) void proj_gemm_k(
    const float* __restrict__ xT, const float* __restrict__ wpT,
    float* __restrict__ qraw, float* __restrict__ kraw, float* __restrict__ vraw,
    unsigned int* __restrict__ amax)
{
    __shared__ __align__(16) float xs[2][16][64];
    __shared__ __align__(16) float wsb[2][16][64];
    __shared__ float redmax[4];
    int tid = threadIdx.x;
    int tx = tid & 15, ty = tid >> 4;
    int lane = tid & 63, w = tid >> 6;
    int t0 = blockIdx.x * 64;
    int o0g = blockIdx.y * 64;
    int mtx = o0g >> 9;                        // 0=q 1=k 2=v
    int h = (o0g >> 6) & 7;
    float* dst = mtx == 0 ? qraw : (mtx == 1 ? kraw : vraw);
    float acc[4][4];
#pragma unroll
    for (int i = 0; i < 4; ++i)
#pragma unroll
        for (int j = 0; j < 4; ++j) acc[i][j] = 0.f;

    int krow = w * 4 + (lane >> 4);            // this lane's source k-row in tile
    int kcol = (lane & 15) * 4;                // this lane's 16B chunk

    // stage tile kt into buffer buf (per wave: 2 DMA insts)
    const float* xsrc = xT + (size_t)krow * 8192 + t0 + kcol;
    const float* wsrc = wpT + (size_t)krow * 1536 + o0g + kcol;

    dma16(xsrc, &xs[0][w * 4][0]);
    dma16(wsrc, &wsb[0][w * 4][0]);
    __syncthreads();                            // drains vmcnt+lgkm, barrier

    for (int kt = 0; kt < 32; ++kt) {
        int buf = kt & 1;
        if (kt + 1 < 32) {
            size_t ko = (size_t)(kt + 1) * 16;
            dma16(xsrc + ko * 8192, &xs[buf ^ 1][w * 4][0]);
            dma16(wsrc + ko * 1536, &wsb[buf ^ 1][w * 4][0]);
        }
#pragma unroll
        for (int kk = 0; kk < 16; ++kk) {
            float4 a = *(const float4*)&xs[buf][kk][ty * 4];
            float4 b = *(const float4*)&wsb[buf][kk][tx * 4];
            outer4(acc, a, b);
        }
        __syncthreads();                        // all waves done with buf; next DMA drained
    }

    float mx = 0.f;
#pragma unroll
    for (int i = 0; i < 4; ++i) {
        int t = t0 + ty * 4 + i;
        int b = t >> 10, n = t & 1023;
        float4 v4 = make_float4(acc[i][0], acc[i][1], acc[i][2], acc[i][3]);
        *(float4*)(dst + ((size_t)(b * 8 + h) * 1024 + n) * 64 + tx * 4) = v4;
        mx = fmaxf(mx, fmaxf(fmaxf(fabsf(v4.x), fabsf(v4.y)),
                             fmaxf(fabsf(v4.z), fabsf(v4.w))));
    }
    if (mtx < 2) {
#pragma unroll
        for (int off = 32; off > 0; off >>= 1) mx = fmaxf(mx, __shfl_down(mx, off));
        if ((tid & 63) == 0) redmax[tid >> 6] = mx;
        __syncthreads();
        if (tid == 0) {
            float m2 = fmaxf(fmaxf(redmax[0], redmax[1]), fmaxf(redmax[2], redmax[3]));
            atomicMax(&amax[mtx], __float_as_uint(m2));
        }
    }
}

// ---------------------------------------------------------------------------
// K2b: q AND k raw fp32 -> int8 levels as exact bf16, one launch (grid.y=2).
// ---------------------------------------------------------------------------
__global__ __launch_bounds__(256) void quant2_k(
    const float* __restrict__ qraw, const float* __restrict__ kraw,
    const unsigned int* __restrict__ amax,
    unsigned short* __restrict__ qlv, unsigned short* __restrict__ klv)
{
    int m = blockIdx.y;
    const float* raw = m ? kraw : qraw;
    unsigned short* lv = m ? klv : qlv;
    float scale = fmaxf(__uint_as_float(amax[m]) / 127.f, 1e-8f);
    int i = blockIdx.x * 256 + threadIdx.x;          // n4 = 1048576
    float4 v = ((const float4*)raw)[i];
    float l0 = fminf(fmaxf(rintf(v.x / scale), -127.f), 127.f);
    float l1 = fminf(fmaxf(rintf(v.y / scale), -127.f), 127.f);
    float l2 = fminf(fmaxf(rintf(v.z / scale), -127.f), 127.f);
    float l3 = fminf(fmaxf(rintf(v.w / scale), -127.f), 127.f);
    ushort4 o;
    o.x = bf16_exact(l0); o.y = bf16_exact(l1);
    o.z = bf16_exact(l2); o.w = bf16_exact(l3);
    ((ushort4*)lv)[i] = o;
}

// ---------------------------------------------------------------------------
// K2c: v (bh,n,64) fp32 -> transposed SINGLE bf16 (bh,d=64,m=1024).
// ---------------------------------------------------------------------------
__global__ __launch_bounds__(256) void vtrans_k(
    const float* __restrict__ vb, unsigned short* __restrict__ vt)
{
    __shared__ float ls[64][69];
    int tid = threadIdx.x;
    int mt = blockIdx.x, bh = blockIdx.y;
#pragma unroll
    for (int l = 0; l < 4; ++l) {
        int idx = l * 256 + tid;
        int r = idx >> 4, c4 = idx & 15;
        float4 v = *(const float4*)(vb + (size_t)(bh * 1024 + mt * 64 + r) * 64 + c4 * 4);
        ls[r][c4 * 4 + 0] = v.x; ls[r][c4 * 4 + 1] = v.y;
        ls[r][c4 * 4 + 2] = v.z; ls[r][c4 * 4 + 3] = v.w;
    }
    __syncthreads();
#pragma unroll
    for (int l = 0; l < 4; ++l) {
        int idx = l * 256 + tid;
        int d = idx >> 4, mg = idx & 15;
        ushort4 hi;
        hi.x = bf16_rne(ls[mg * 4 + 0][d]);
        hi.y = bf16_rne(ls[mg * 4 + 1][d]);
        hi.z = bf16_rne(ls[mg * 4 + 2][d]);
        hi.w = bf16_rne(ls[mg * 4 + 3][d]);
        *(ushort4*)(vt + (size_t)(bh * 64 + d) * 1024 + mt * 64 + mg * 4) = hi;
    }
}

// ---------------------------------------------------------------------------
// K3a: barrier-free MFMA scores + bitmask + online (m,l) over a column
// QUARTER (256 cols). Grid (16 qt, 64 bh, 4 quarter) -> 16384 waves.
// ---------------------------------------------------------------------------
__global__ __launch_bounds__(256) void attn_stats_k(
    const unsigned short* __restrict__ qlv, const unsigned short* __restrict__ klv,
    const unsigned long long* __restrict__ bm, const unsigned int* __restrict__ amax,
    float2* __restrict__ psums)
{
    int tid = threadIdx.x;
    int lane = tid & 63, w = tid >> 6;
    int m_ = lane & 15, quad = lane >> 4;
    int qt = blockIdx.x, bh = blockIdx.y, qtr = blockIdx.z;
    int b = bh >> 3;
    int rowbase = qt * 64 + w * 16;
    float sq = fmaxf(__uint_as_float(amax[0]) / 127.f, 1e-8f);
    float sk = fmaxf(__uint_as_float(amax[1]) / 127.f, 1e-8f);
    float ss = sq * sk;

    const unsigned short* qp = qlv + ((size_t)bh * 1024 + rowbase + m_) * 64;
    short8 Aq0 = *(const short8*)(qp + quad * 8);
    short8 Aq1 = *(const short8*)(qp + 32 + quad * 8);
    const unsigned short* kbase = klv + (size_t)bh * 1024 * 64;
    const unsigned long long* bmb = bm + ((size_t)b * 1024 + rowbase) * 16;

    float mrun[4], lrun[4];
#pragma unroll
    for (int r = 0; r < 4; ++r) { mrun[r] = -1e9f; lrun[r] = 0.f; }

    for (int ci = 0; ci < 4; ++ci) {
        int c = qtr * 4 + ci;
        unsigned long long mk[4];
#pragma unroll
        for (int r = 0; r < 4; ++r) mk[r] = bmb[(quad * 4 + r) * 16 + c];
        float sv[4][4];
#pragma unroll
        for (int s = 0; s < 4; ++s) {
            const unsigned short* kp = kbase + (size_t)(c * 64 + s * 16 + m_) * 64;
            short8 B0 = *(const short8*)(kp + quad * 8);
            short8 B1 = *(const short8*)(kp + 32 + quad * 8);
            floatx4 Cv = {0.f, 0.f, 0.f, 0.f};
            Cv = __builtin_amdgcn_mfma_f32_16x16x32_bf16(Aq0, B0, Cv, 0, 0, 0);
            Cv = __builtin_amdgcn_mfma_f32_16x16x32_bf16(Aq1, B1, Cv, 0, 0, 0);
            int colbit = s * 16 + m_;
#pragma unroll
            for (int r = 0; r < 4; ++r)
                sv[r][s] = ((mk[r] >> colbit) & 1ull) ? Cv[r] * ss : -1e9f;
        }
#pragma unroll
        for (int r = 0; r < 4; ++r) {
            float tm = fmaxf(fmaxf(sv[r][0], sv[r][1]), fmaxf(sv[r][2], sv[r][3]));
            float mn = fmaxf(mrun[r], tm);
            float e = __expf(sv[r][0] - mn) + __expf(sv[r][1] - mn)
                    + __expf(sv[r][2] - mn) + __expf(sv[r][3] - mn);
            lrun[r] = fmaf(lrun[r], __expf(mrun[r] - mn), e);
            mrun[r] = mn;
        }
    }

#pragma unroll
    for (int r = 0; r < 4; ++r) {
        float m = mrun[r], l = lrun[r];
#pragma unroll
        for (int off = 1; off < 16; off <<= 1) {
            float mo = __shfl_xor(m, off);
            float lo = __shfl_xor(l, off);
            float mn = fmaxf(m, mo);
            l = l * __expf(m - mn) + lo * __expf(mo - mn);
            m = mn;
        }
        if (m_ == 0)
            psums[(size_t)qtr * 65536 + (size_t)bh * 1024 + rowbase + quad * 4 + r] =
                make_float2(m, l);
    }
}

// ---------------------------------------------------------------------------
// K3a2: merge 4 quarter-(m,l) into rowstats; global attn amax = max 1/l.
// ---------------------------------------------------------------------------
__global__ __launch_bounds__(256) void stats_merge_k(
    const float2* __restrict__ ps, float2* __restrict__ rowstats,
    unsigned int* __restrict__ amax_attn)
{
    int row = blockIdx.x * 256 + threadIdx.x;        // 65536 rows
    float2 a = ps[row];
    float m = a.x, l = a.y;
#pragma unroll
    for (int q = 1; q < 4; ++q) {
        float2 bq = ps[(size_t)q * 65536 + row];
        float mn = fmaxf(m, bq.x);
        l = l * __expf(m - mn) + bq.y * __expf(bq.x - mn);
        m = mn;
    }
    rowstats[row] = make_float2(m, l);
    float inv = 1.0f / l;
#pragma unroll
    for (int off = 1; off < 64; off <<= 1) inv = fmaxf(inv, __shfl_xor(inv, off));
    if ((threadIdx.x & 63) == 0) atomicMax(amax_attn, __float_as_uint(inv));
}

// ---------------------------------------------------------------------------
// K3b: round-7 measured-best. Recompute scores (bit-identical), quantize attn
// (coalesced float4 writes from LDS), fused P@V via MFMA (single-bf16 V,
// fragments preloaded before the LDS wait); column-HALF split (z=2), out via
// fp32 atomicAdd into zeroed out.
// ---------------------------------------------------------------------------
__global__ __launch_bounds__(256) void attn_out_k(
    const unsigned short* __restrict__ qlv, const unsigned short* __restrict__ klv,
    const unsigned short* __restrict__ vt,
    const unsigned long long* __restrict__ bm, const unsigned int* __restrict__ amax,
    const float2* __restrict__ rowstats,
    float* __restrict__ attn, float* __restrict__ out)
{
    __shared__ unsigned short pl[4][2][16][68];      // [wave][dbuf][row][col(+pad)]
    int tid = threadIdx.x;
    int lane = tid & 63, w = tid >> 6;
    int m_ = lane & 15, quad = lane >> 4;
    int qt = blockIdx.x, bh = blockIdx.y, half = blockIdx.z;
    int b = bh >> 3, h = bh & 7;
    int rowbase = qt * 64 + w * 16;
    float sq = fmaxf(__uint_as_float(amax[0]) / 127.f, 1e-8f);
    float sk = fmaxf(__uint_as_float(amax[1]) / 127.f, 1e-8f);
    float ss = sq * sk;
    float sa = fmaxf(__uint_as_float(amax[2]) / 127.f, 1e-8f);
    float inv_sa = 1.0f / sa;

    const unsigned short* qp = qlv + ((size_t)bh * 1024 + rowbase + m_) * 64;
    short8 Aq0 = *(const short8*)(qp + quad * 8);
    short8 Aq1 = *(const short8*)(qp + 32 + quad * 8);
    const unsigned short* kbase = klv + (size_t)bh * 1024 * 64;
    const unsigned long long* bmb = bm + ((size_t)b * 1024 + rowbase) * 16;

    float mrow[4], rlr[4];
#pragma unroll
    for (int r = 0; r < 4; ++r) {
        float2 st = rowstats[(size_t)bh * 1024 + rowbase + quad * 4 + r];
        mrow[r] = st.x;
        rlr[r] = 1.0f / st.y;
    }
    floatx4 acc[4];
#pragma unroll
    for (int r = 0; r < 4; ++r) acc[r] = (floatx4){0.f, 0.f, 0.f, 0.f};

    float* attn_b = attn + ((size_t)bh << 20);

    for (int ci = 0; ci < 8; ++ci) {
        int c = half * 8 + ci;
        // V fragments first: independent of score path, overlap its latency
        short8 Vb0[4], Vb1[4];
#pragma unroll
        for (int dt = 0; dt < 4; ++dt) {
            const unsigned short* vp = vt + ((size_t)(bh * 64 + dt * 16 + m_)) * 1024 + c * 64;
            Vb0[dt] = *(const short8*)(vp + quad * 8);
            Vb1[dt] = *(const short8*)(vp + 32 + quad * 8);
        }
        unsigned long long mk[4];
#pragma unroll
        for (int r = 0; r < 4; ++r) mk[r] = bmb[(quad * 4 + r) * 16 + c];
        unsigned short* plw = &pl[w][ci & 1][0][0];
#pragma unroll
        for (int s = 0; s < 4; ++s) {
            const unsigned short* kp = kbase + (size_t)(c * 64 + s * 16 + m_) * 64;
            short8 B0 = *(const short8*)(kp + quad * 8);
            short8 B1 = *(const short8*)(kp + 32 + quad * 8);
            floatx4 Cv = {0.f, 0.f, 0.f, 0.f};
            Cv = __builtin_amdgcn_mfma_f32_16x16x32_bf16(Aq0, B0, Cv, 0, 0, 0);
            Cv = __builtin_amdgcn_mfma_f32_16x16x32_bf16(Aq1, B1, Cv, 0, 0, 0);
            int colbit = s * 16 + m_;
#pragma unroll
            for (int r = 0; r < 4; ++r) {
                float sval = ((mk[r] >> colbit) & 1ull) ? Cv[r] * ss : -1e9f;
                float p = __expf(sval - mrow[r]) * rlr[r];   // round-3 op order
                float lv = fminf(rintf(p * inv_sa), 127.f);
                plw[(quad * 4 + r) * 68 + colbit] = bf16_exact(lv);
            }
        }
        __asm__ volatile("s_waitcnt lgkmcnt(0)" ::: "memory");
        short8 Ap0 = *(const short8*)&pl[w][ci & 1][m_][quad * 8];
        short8 Ap1 = *(const short8*)&pl[w][ci & 1][m_][32 + quad * 8];
#pragma unroll
        for (int dt = 0; dt < 4; ++dt) {
            acc[dt] = __builtin_amdgcn_mfma_f32_16x16x32_bf16(Ap0, Vb0[dt], acc[dt], 0, 0, 0);
            acc[dt] = __builtin_amdgcn_mfma_f32_16x16x32_bf16(Ap1, Vb1[dt], acc[dt], 0, 0, 0);
        }
        // coalesced attn write: 4 x (b64 LDS read -> float4 store, 256B rows)
#pragma unroll
        for (int it = 0; it < 4; ++it) {
            int rrow = it * 4 + quad, col = m_ * 4;
            uint2 pk = *(const uint2*)&pl[w][ci & 1][rrow][col];
            float4 av;
            av.x = bf16_to_f((unsigned short)(pk.x & 0xffff)) * sa;
            av.y = bf16_to_f((unsigned short)(pk.x >> 16)) * sa;
            av.z = bf16_to_f((unsigned short)(pk.y & 0xffff)) * sa;
            av.w = bf16_to_f((unsigned short)(pk.y >> 16)) * sa;
            *(float4*)(attn_b + (((size_t)(rowbase + rrow)) << 10) + c * 64 + col) = av;
        }
    }
#pragma unroll
    for (int dt = 0; dt < 4; ++dt)
#pragma unroll
        for (int r = 0; r < 4; ++r) {
            int n = rowbase + quad * 4 + r;
            int d = dt * 16 + m_;
            atomicAdd(&out[(size_t)(b * 1024 + n) * 512 + h * 64 + d], acc[dt][r] * sa);
        }
}

// ---------------------------------------------------------------------------
extern "C" void kernel_launch(void* const* d_in, const int* in_sizes, int n_in,
                              void* d_out, int out_size, void* d_ws, size_t ws_size,
                              hipStream_t stream)
{
    (void)in_sizes; (void)n_in; (void)out_size; (void)ws_size;
    const float* x   = (const float*)d_in[0];
    const int*   adj = (const int*)d_in[1];
    const float* W_q = (const float*)d_in[2];
    const float* A_q = (const float*)d_in[3];
    const float* B_q = (const float*)d_in[4];
    const float* m_q = (const float*)d_in[5];
    const float* W_k = (const float*)d_in[6];
    const float* A_k = (const float*)d_in[7];
    const float* B_k = (const float*)d_in[8];
    const float* m_k = (const float*)d_in[9];
    const float* W_v = (const float*)d_in[10];
    const float* A_v = (const float*)d_in[11];
    const float* B_v = (const float*)d_in[12];
    const float* m_v = (const float*)d_in[13];

    char* ws = (char*)d_ws;
    float* wpT          = (float*)(ws + OB_WPT);
    float* xT           = (float*)(ws + OB_XT);
    float* qraw         = (float*)(ws + OB_QRAW);
    float* kraw         = (float*)(ws + OB_KRAW);
    float* vraw         = (float*)(ws + OB_VRAW);
    unsigned short* qlv = (unsigned short*)(ws + OB_QLV);   // overlays vraw
    unsigned short* klv = (unsigned short*)(ws + OB_KLV);   // overlays vraw
    unsigned short* vt  = (unsigned short*)(ws + OB_VT);    // overlays xT
    float2* rowstats    = (float2*)(ws + OB_RS);
    float2* psums       = (float2*)(ws + OB_PS);            // overlays qraw
    unsigned long long* bmask = (unsigned long long*)(ws + OB_BM);
    unsigned int* amax  = (unsigned int*)(ws + OB_AMAX);

    float* out_base  = (float*)d_out;          // (b, n, 512)
    float* attn_base = out_base + 4194304;     // (b, h, n, m)

    hipMemsetAsync(amax, 0, 16, stream);
    hipMemsetAsync(out_base, 0, 16777216, stream);   // out accumulated via atomics

    adj_bits_k<<<32768, 256, 0, stream>>>(adj, bmask);
    transp_k<<<dim3(8, 128), 256, 0, stream>>>(x, xT, 8192, 512);   // x^T

    build_wp3_k<<<dim3(512, 3), 256, 0, stream>>>(W_q, A_q, B_q, m_q,
                                                  W_k, A_k, B_k, m_k,
                                                  W_v, A_v, B_v, m_v, wpT);
    proj_gemm_k<<<dim3(128, 24), 256, 0, stream>>>(xT, wpT, qraw, kraw, vraw, amax);
    // vtrans BEFORE quant2: qlv/klv overlay vraw, which dies here
    vtrans_k<<<dim3(16, 64), 256, 0, stream>>>(vraw, vt);
    quant2_k<<<dim3(4096, 2), 256, 0, stream>>>(qraw, kraw, amax, qlv, klv);

    attn_stats_k<<<dim3(16, 64, 4), 256, 0, stream>>>(qlv, klv, bmask, amax, psums);
    stats_merge_k<<<256, 256, 0, stream>>>(psums, rowstats, amax + 2);
    attn_out_k<<<dim3(16, 64, 2), 256, 0, stream>>>(qlv, klv, vt, bmask, amax,
                                                    rowstats, attn_base, out_base);
}

// Round 11
// 738.360 us; speedup vs baseline: 1.0049x; 1.0049x over previous
//
#include <hip/hip_runtime.h>
#include <math.h>

// Problem constants: B=8, N=1024, FIN=FOUT=512, H=8, HD=64, BH=64

typedef __attribute__((ext_vector_type(8))) short short8;    // 8 bf16 (4 VGPRs)
typedef __attribute__((ext_vector_type(4))) float floatx4;   // MFMA C/D

// Workspace byte offsets (~89 MB).
// Overlays: VT overlays XT (dead after proj); QLV/KLV overlay VRAW (vtrans
// runs BEFORE quant2); PS overlays QRAW (dead after quant2).
#define OB_WPT   0ull           // 3145728   Wp^T fp32 [k=512][o=1536]
#define OB_XT    3145728ull     // 33554432  x^T fp32 [k=512][t=8192]
#define OB_VT    OB_XT          // 8388608   v^T bf16 (overlay, after proj)
#define OB_QRAW  36700160ull    // 16777216  q raw fp32 (b,h,n,d)
#define OB_PS    OB_QRAW        // 2097152   partial (m,l) x4 (overlay)
#define OB_KRAW  53477376ull    // 16777216  k raw fp32
#define OB_VRAW  70254592ull    // 16777216  v raw fp32
#define OB_QLV   70254592ull    // 8388608   q levels bf16 (overlay vraw lo)
#define OB_KLV   78643200ull    // 8388608   k levels bf16 (overlay vraw hi)
#define OB_RS    87031808ull    // 524288    rowstats float2
#define OB_BM    87556096ull    // 1048576   adj bitmask u64
#define OB_AMAX  88604672ull    // 16        amax_q, amax_k, amax_attn

__device__ __forceinline__ unsigned short bf16_rne(float f) {
    unsigned int u = __float_as_uint(f);
    unsigned int r = u + 0x7fffu + ((u >> 16) & 1u);
    return (unsigned short)(r >> 16);
}
__device__ __forceinline__ float bf16_to_f(unsigned short h) {
    return __uint_as_float(((unsigned int)h) << 16);
}
// exact for values already representable in bf16 (integer levels |x|<=127)
__device__ __forceinline__ unsigned short bf16_exact(float f) {
    return (unsigned short)(__float_as_uint(f) >> 16);
}

// async global->LDS, 16 B per lane; gptr is per-lane, LDS dest = base+lane*16
__device__ __forceinline__ void dma16(const float* g, float* l) {
    __builtin_amdgcn_global_load_lds(
        (__attribute__((address_space(1))) void*)(void*)g,
        (__attribute__((address_space(3))) void*)(void*)l, 16, 0, 0);
}

// ---------------------------------------------------------------------------
// K0: adjacency (8,1024,1024) i32 -> bitmask (8,1024,16) u64. One word/wave.
// ---------------------------------------------------------------------------
__global__ __launch_bounds__(256) void adj_bits_k(
    const int* __restrict__ adj, unsigned long long* __restrict__ bm)
{
    int tid = threadIdx.x;
    int wv = tid >> 6, lane = tid & 63;
    size_t word = (size_t)blockIdx.x * 4 + wv;       // 131072 words total
    int a = adj[word * 64 + lane];
    unsigned long long m = __ballot(a != 0);
    if (lane == 0) bm[word] = m;
}

// ---------------------------------------------------------------------------
// K0b: fp32 transpose dst[c][r] = src[r][c]; 64x64 LDS tiles, coalesced both
// sides. Pure data movement (bit-exact). grid (C/64, R/64).
// ---------------------------------------------------------------------------
__global__ __launch_bounds__(256) void transp_k(
    const float* __restrict__ src, float* __restrict__ dst, int R, int C)
{
    __shared__ float ls[64][65];
    int tid = threadIdx.x;
    int ct = blockIdx.x, rt = blockIdx.y;
#pragma unroll
    for (int l = 0; l < 4; ++l) {
        int idx = l * 256 + tid;
        int r = idx >> 4, c4 = idx & 15;
        float4 v = *(const float4*)(src + (size_t)(rt * 64 + r) * C + ct * 64 + c4 * 4);
        ls[r][c4 * 4 + 0] = v.x; ls[r][c4 * 4 + 1] = v.y;
        ls[r][c4 * 4 + 2] = v.z; ls[r][c4 * 4 + 3] = v.w;
    }
    __syncthreads();
#pragma unroll
    for (int l = 0; l < 4; ++l) {
        int idx = l * 256 + tid;
        int c = idx >> 4, r4 = idx & 15;
        float4 o = make_float4(ls[r4 * 4 + 0][c], ls[r4 * 4 + 1][c],
                               ls[r4 * 4 + 2][c], ls[r4 * 4 + 3][c]);
        *(float4*)(dst + (size_t)(ct * 64 + c) * R + rt * 64 + r4 * 4) = o;
    }
}

// ---------------------------------------------------------------------------
// K1: all three DoRA-merged weights, written TRANSPOSED: WpT[k][mtx*512+o].
// Per-row numerics identical to all passing rounds.
// ---------------------------------------------------------------------------
__global__ __launch_bounds__(256) void build_wp3_k(
    const float* __restrict__ W_q, const float* __restrict__ A_q,
    const float* __restrict__ B_q, const float* __restrict__ m_q,
    const float* __restrict__ W_k, const float* __restrict__ A_k,
    const float* __restrict__ B_k, const float* __restrict__ m_k,
    const float* __restrict__ W_v, const float* __restrict__ A_v,
    const float* __restrict__ B_v, const float* __restrict__ m_v,
    float* __restrict__ wpT)
{
    __shared__ float brow[16];
    __shared__ __align__(16) float wd[512];
    __shared__ float red[5];
    int o = blockIdx.x;
    int mtx = blockIdx.y;
    const float* W   = mtx == 0 ? W_q : (mtx == 1 ? W_k : W_v);
    const float* A   = mtx == 0 ? A_q : (mtx == 1 ? A_k : A_v);
    const float* Bm  = mtx == 0 ? B_q : (mtx == 1 ? B_k : B_v);
    const float* mag = mtx == 0 ? m_q : (mtx == 1 ? m_k : m_v);
    int ocol = mtx * 512 + o;
    int tid = threadIdx.x;
    if (tid < 16) brow[tid] = Bm[o * 16 + tid];
    __syncthreads();
    float ss = 0.f;
    for (int i = tid; i < 512; i += 256) {
        float acc = W[o * 512 + i];
#pragma unroll
        for (int r = 0; r < 16; ++r) acc = fmaf(brow[r], A[r * 512 + i], acc);
        wd[i] = acc;
        ss = fmaf(acc, acc, ss);
    }
#pragma unroll
    for (int off = 32; off > 0; off >>= 1) ss += __shfl_down(ss, off);
    int lane = tid & 63, wv = tid >> 6;
    if (lane == 0) red[wv] = ss;
    __syncthreads();
    if (tid == 0) red[4] = mag[o] / sqrtf(red[0] + red[1] + red[2] + red[3]);
    __syncthreads();
    float scl = red[4];
    for (int i = tid; i < 512; i += 256)
        wpT[(size_t)i * 1536 + ocol] = wd[i] * scl;
}

// ---------------------------------------------------------------------------
// K2: FUSED fp32 projection, 128x128 tile, 8x8 per thread (4x the FLOP per
// LDS byte and per barrier vs the 64x64/4x4 version). Per-element k-order is
// sequential fmaf k=0..511 -> BIT-IDENTICAL q/k/v raw values and amax vs all
// passing rounds. DMA-staged (global_load_lds 16B), double-buffered LDS.
// grid (64 t-tiles, 12 o-tiles): o tiles 0-3 q, 4-7 k, 8-11 v.
// ---------------------------------------------------------------------------
__global__ __launch_bounds__(256) void proj_gemm_k(
    const float* __restrict__ xT, const float* __restrict__ wpT,
    float* __restrict__ qraw, float* __restrict__ kraw, float* __restrict__ vraw,
    unsigned int* __restrict__ amax)
{
    __shared__ __align__(16) float xs[2][16][128];
    __shared__ __align__(16) float wsb[2][16][128];
    __shared__ float redmax[4];
    int tid = threadIdx.x;
    int tx = tid & 15, ty = tid >> 4;
    int lane = tid & 63, w = tid >> 6;
    int t0 = blockIdx.x * 128;
    int o0 = blockIdx.y * 128;
    int mtx = o0 >> 9;                         // 0=q 1=k 2=v (128 | 512)
    float* dst = mtx == 0 ? qraw : (mtx == 1 ? kraw : vraw);
    float acc[8][8];
#pragma unroll
    for (int i = 0; i < 8; ++i)
#pragma unroll
        for (int j = 0; j < 8; ++j) acc[i][j] = 0.f;

    // wave w stages rows w*4..w*4+3 of each 16x128 tile (2 rows / DMA instr)
    int sub = lane >> 5;                       // row within instr (0/1)
    int col4 = (lane & 31) * 4;                // 16B chunk in the 128-float row
    const float* xs0 = xT + (size_t)(w * 4 + sub) * 8192 + t0 + col4;
    const float* xs1 = xT + (size_t)(w * 4 + 2 + sub) * 8192 + t0 + col4;
    const float* ws0 = wpT + (size_t)(w * 4 + sub) * 1536 + o0 + col4;
    const float* ws1 = wpT + (size_t)(w * 4 + 2 + sub) * 1536 + o0 + col4;

    dma16(xs0, &xs[0][w * 4][0]);
    dma16(xs1, &xs[0][w * 4 + 2][0]);
    dma16(ws0, &wsb[0][w * 4][0]);
    dma16(ws1, &wsb[0][w * 4 + 2][0]);
    __syncthreads();

    for (int kt = 0; kt < 32; ++kt) {
        int buf = kt & 1;
        if (kt + 1 < 32) {
            size_t kox = (size_t)(kt + 1) * 16 * 8192;
            size_t kow = (size_t)(kt + 1) * 16 * 1536;
            dma16(xs0 + kox, &xs[buf ^ 1][w * 4][0]);
            dma16(xs1 + kox, &xs[buf ^ 1][w * 4 + 2][0]);
            dma16(ws0 + kow, &wsb[buf ^ 1][w * 4][0]);
            dma16(ws1 + kow, &wsb[buf ^ 1][w * 4 + 2][0]);
        }
#pragma unroll
        for (int kk = 0; kk < 16; ++kk) {
            float4 a0 = *(const float4*)&xs[buf][kk][ty * 8];
            float4 a1 = *(const float4*)&xs[buf][kk][ty * 8 + 4];
            float4 b0 = *(const float4*)&wsb[buf][kk][tx * 8];
            float4 b1 = *(const float4*)&wsb[buf][kk][tx * 8 + 4];
            float av[8] = {a0.x, a0.y, a0.z, a0.w, a1.x, a1.y, a1.z, a1.w};
            float bv[8] = {b0.x, b0.y, b0.z, b0.w, b1.x, b1.y, b1.z, b1.w};
#pragma unroll
            for (int i = 0; i < 8; ++i)
#pragma unroll
                for (int j = 0; j < 8; ++j)
                    acc[i][j] = fmaf(av[i], bv[j], acc[i][j]);
        }
        __syncthreads();
    }

    float mx = 0.f;
#pragma unroll
    for (int i = 0; i < 8; ++i) {
        int t = t0 + ty * 8 + i;
        int b = t >> 10, n = t & 1023;
#pragma unroll
        for (int jh = 0; jh < 2; ++jh) {
            int col = o0 + tx * 8 + jh * 4;    // 4-aligned, within one head
            int h = (col >> 6) & 7, d = col & 63;
            float4 v4 = make_float4(acc[i][jh * 4 + 0], acc[i][jh * 4 + 1],
                                    acc[i][jh * 4 + 2], acc[i][jh * 4 + 3]);
            *(float4*)(dst + ((size_t)(b * 8 + h) * 1024 + n) * 64 + d) = v4;
            mx = fmaxf(mx, fmaxf(fmaxf(fabsf(v4.x), fabsf(v4.y)),
                                 fmaxf(fabsf(v4.z), fabsf(v4.w))));
        }
    }
    if (mtx < 2) {
#pragma unroll
        for (int off = 32; off > 0; off >>= 1) mx = fmaxf(mx, __shfl_down(mx, off));
        if ((tid & 63) == 0) redmax[tid >> 6] = mx;
        __syncthreads();
        if (tid == 0) {
            float m2 = fmaxf(fmaxf(redmax[0], redmax[1]), fmaxf(redmax[2], redmax[3]));
            atomicMax(&amax[mtx], __float_as_uint(m2));
        }
    }
}

// ---------------------------------------------------------------------------
// K2b: q AND k raw fp32 -> int8 levels as exact bf16, one launch (grid.y=2).
// ---------------------------------------------------------------------------
__global__ __launch_bounds__(256) void quant2_k(
    const float* __restrict__ qraw, const float* __restrict__ kraw,
    const unsigned int* __restrict__ amax,
    unsigned short* __restrict__ qlv, unsigned short* __restrict__ klv)
{
    int m = blockIdx.y;
    const float* raw = m ? kraw : qraw;
    unsigned short* lv = m ? klv : qlv;
    float scale = fmaxf(__uint_as_float(amax[m]) / 127.f, 1e-8f);
    int i = blockIdx.x * 256 + threadIdx.x;          // n4 = 1048576
    float4 v = ((const float4*)raw)[i];
    float l0 = fminf(fmaxf(rintf(v.x / scale), -127.f), 127.f);
    float l1 = fminf(fmaxf(rintf(v.y / scale), -127.f), 127.f);
    float l2 = fminf(fmaxf(rintf(v.z / scale), -127.f), 127.f);
    float l3 = fminf(fmaxf(rintf(v.w / scale), -127.f), 127.f);
    ushort4 o;
    o.x = bf16_exact(l0); o.y = bf16_exact(l1);
    o.z = bf16_exact(l2); o.w = bf16_exact(l3);
    ((ushort4*)lv)[i] = o;
}

// ---------------------------------------------------------------------------
// K2c: v (bh,n,64) fp32 -> transposed SINGLE bf16 (bh,d=64,m=1024).
// ---------------------------------------------------------------------------
__global__ __launch_bounds__(256) void vtrans_k(
    const float* __restrict__ vb, unsigned short* __restrict__ vt)
{
    __shared__ float ls[64][69];
    int tid = threadIdx.x;
    int mt = blockIdx.x, bh = blockIdx.y;
#pragma unroll
    for (int l = 0; l < 4; ++l) {
        int idx = l * 256 + tid;
        int r = idx >> 4, c4 = idx & 15;
        float4 v = *(const float4*)(vb + (size_t)(bh * 1024 + mt * 64 + r) * 64 + c4 * 4);
        ls[r][c4 * 4 + 0] = v.x; ls[r][c4 * 4 + 1] = v.y;
        ls[r][c4 * 4 + 2] = v.z; ls[r][c4 * 4 + 3] = v.w;
    }
    __syncthreads();
#pragma unroll
    for (int l = 0; l < 4; ++l) {
        int idx = l * 256 + tid;
        int d = idx >> 4, mg = idx & 15;
        ushort4 hi;
        hi.x = bf16_rne(ls[mg * 4 + 0][d]);
        hi.y = bf16_rne(ls[mg * 4 + 1][d]);
        hi.z = bf16_rne(ls[mg * 4 + 2][d]);
        hi.w = bf16_rne(ls[mg * 4 + 3][d]);
        *(ushort4*)(vt + (size_t)(bh * 64 + d) * 1024 + mt * 64 + mg * 4) = hi;
    }
}

// ---------------------------------------------------------------------------
// K3a: barrier-free MFMA scores + bitmask + online (m,l) over a column
// QUARTER (256 cols). Grid (16 qt, 64 bh, 4 quarter) -> 16384 waves.
// ---------------------------------------------------------------------------
__global__ __launch_bounds__(256) void attn_stats_k(
    const unsigned short* __restrict__ qlv, const unsigned short* __restrict__ klv,
    const unsigned long long* __restrict__ bm, const unsigned int* __restrict__ amax,
    float2* __restrict__ psums)
{
    int tid = threadIdx.x;
    int lane = tid & 63, w = tid >> 6;
    int m_ = lane & 15, quad = lane >> 4;
    int qt = blockIdx.x, bh = blockIdx.y, qtr = blockIdx.z;
    int b = bh >> 3;
    int rowbase = qt * 64 + w * 16;
    float sq = fmaxf(__uint_as_float(amax[0]) / 127.f, 1e-8f);
    float sk = fmaxf(__uint_as_float(amax[1]) / 127.f, 1e-8f);
    float ss = sq * sk;

    const unsigned short* qp = qlv + ((size_t)bh * 1024 + rowbase + m_) * 64;
    short8 Aq0 = *(const short8*)(qp + quad * 8);
    short8 Aq1 = *(const short8*)(qp + 32 + quad * 8);
    const unsigned short* kbase = klv + (size_t)bh * 1024 * 64;
    const unsigned long long* bmb = bm + ((size_t)b * 1024 + rowbase) * 16;

    float mrun[4], lrun[4];
#pragma unroll
    for (int r = 0; r < 4; ++r) { mrun[r] = -1e9f; lrun[r] = 0.f; }

    for (int ci = 0; ci < 4; ++ci) {
        int c = qtr * 4 + ci;
        unsigned long long mk[4];
#pragma unroll
        for (int r = 0; r < 4; ++r) mk[r] = bmb[(quad * 4 + r) * 16 + c];
        float sv[4][4];
#pragma unroll
        for (int s = 0; s < 4; ++s) {
            const unsigned short* kp = kbase + (size_t)(c * 64 + s * 16 + m_) * 64;
            short8 B0 = *(const short8*)(kp + quad * 8);
            short8 B1 = *(const short8*)(kp + 32 + quad * 8);
            floatx4 Cv = {0.f, 0.f, 0.f, 0.f};
            Cv = __builtin_amdgcn_mfma_f32_16x16x32_bf16(Aq0, B0, Cv, 0, 0, 0);
            Cv = __builtin_amdgcn_mfma_f32_16x16x32_bf16(Aq1, B1, Cv, 0, 0, 0);
            int colbit = s * 16 + m_;
#pragma unroll
            for (int r = 0; r < 4; ++r)
                sv[r][s] = ((mk[r] >> colbit) & 1ull) ? Cv[r] * ss : -1e9f;
        }
#pragma unroll
        for (int r = 0; r < 4; ++r) {
            float tm = fmaxf(fmaxf(sv[r][0], sv[r][1]), fmaxf(sv[r][2], sv[r][3]));
            float mn = fmaxf(mrun[r], tm);
            float e = __expf(sv[r][0] - mn) + __expf(sv[r][1] - mn)
                    + __expf(sv[r][2] - mn) + __expf(sv[r][3] - mn);
            lrun[r] = fmaf(lrun[r], __expf(mrun[r] - mn), e);
            mrun[r] = mn;
        }
    }

#pragma unroll
    for (int r = 0; r < 4; ++r) {
        float m = mrun[r], l = lrun[r];
#pragma unroll
        for (int off = 1; off < 16; off <<= 1) {
            float mo = __shfl_xor(m, off);
            float lo = __shfl_xor(l, off);
            float mn = fmaxf(m, mo);
            l = l * __expf(m - mn) + lo * __expf(mo - mn);
            m = mn;
        }
        if (m_ == 0)
            psums[(size_t)qtr * 65536 + (size_t)bh * 1024 + rowbase + quad * 4 + r] =
                make_float2(m, l);
    }
}

// ---------------------------------------------------------------------------
// K3a2: merge 4 quarter-(m,l) into rowstats; global attn amax = max 1/l.
// ---------------------------------------------------------------------------
__global__ __launch_bounds__(256) void stats_merge_k(
    const float2* __restrict__ ps, float2* __restrict__ rowstats,
    unsigned int* __restrict__ amax_attn)
{
    int row = blockIdx.x * 256 + threadIdx.x;        // 65536 rows
    float2 a = ps[row];
    float m = a.x, l = a.y;
#pragma unroll
    for (int q = 1; q < 4; ++q) {
        float2 bq = ps[(size_t)q * 65536 + row];
        float mn = fmaxf(m, bq.x);
        l = l * __expf(m - mn) + bq.y * __expf(bq.x - mn);
        m = mn;
    }
    rowstats[row] = make_float2(m, l);
    float inv = 1.0f / l;
#pragma unroll
    for (int off = 1; off < 64; off <<= 1) inv = fmaxf(inv, __shfl_xor(inv, off));
    if ((threadIdx.x & 63) == 0) atomicMax(amax_attn, __float_as_uint(inv));
}

// ---------------------------------------------------------------------------
// K3b: round-7 measured-best. Recompute scores (bit-identical), quantize attn
// (coalesced float4 writes from LDS), fused P@V via MFMA (single-bf16 V,
// fragments preloaded before the LDS wait); column-HALF split (z=2), out via
// fp32 atomicAdd into zeroed out.
// ---------------------------------------------------------------------------
__global__ __launch_bounds__(256) void attn_out_k(
    const unsigned short* __restrict__ qlv, const unsigned short* __restrict__ klv,
    const unsigned short* __restrict__ vt,
    const unsigned long long* __restrict__ bm, const unsigned int* __restrict__ amax,
    const float2* __restrict__ rowstats,
    float* __restrict__ attn, float* __restrict__ out)
{
    __shared__ unsigned short pl[4][2][16][68];      // [wave][dbuf][row][col(+pad)]
    int tid = threadIdx.x;
    int lane = tid & 63, w = tid >> 6;
    int m_ = lane & 15, quad = lane >> 4;
    int qt = blockIdx.x, bh = blockIdx.y, half = blockIdx.z;
    int b = bh >> 3, h = bh & 7;
    int rowbase = qt * 64 + w * 16;
    float sq = fmaxf(__uint_as_float(amax[0]) / 127.f, 1e-8f);
    float sk = fmaxf(__uint_as_float(amax[1]) / 127.f, 1e-8f);
    float ss = sq * sk;
    float sa = fmaxf(__uint_as_float(amax[2]) / 127.f, 1e-8f);
    float inv_sa = 1.0f / sa;

    const unsigned short* qp = qlv + ((size_t)bh * 1024 + rowbase + m_) * 64;
    short8 Aq0 = *(const short8*)(qp + quad * 8);
    short8 Aq1 = *(const short8*)(qp + 32 + quad * 8);
    const unsigned short* kbase = klv + (size_t)bh * 1024 * 64;
    const unsigned long long* bmb = bm + ((size_t)b * 1024 + rowbase) * 16;

    float mrow[4], rlr[4];
#pragma unroll
    for (int r = 0; r < 4; ++r) {
        float2 st = rowstats[(size_t)bh * 1024 + rowbase + quad * 4 + r];
        mrow[r] = st.x;
        rlr[r] = 1.0f / st.y;
    }
    floatx4 acc[4];
#pragma unroll
    for (int r = 0; r < 4; ++r) acc[r] = (floatx4){0.f, 0.f, 0.f, 0.f};

    float* attn_b = attn + ((size_t)bh << 20);

    for (int ci = 0; ci < 8; ++ci) {
        int c = half * 8 + ci;
        // V fragments first: independent of score path, overlap its latency
        short8 Vb0[4], Vb1[4];
#pragma unroll
        for (int dt = 0; dt < 4; ++dt) {
            const unsigned short* vp = vt + ((size_t)(bh * 64 + dt * 16 + m_)) * 1024 + c * 64;
            Vb0[dt] = *(const short8*)(vp + quad * 8);
            Vb1[dt] = *(const short8*)(vp + 32 + quad * 8);
        }
        unsigned long long mk[4];
#pragma unroll
        for (int r = 0; r < 4; ++r) mk[r] = bmb[(quad * 4 + r) * 16 + c];
        unsigned short* plw = &pl[w][ci & 1][0][0];
#pragma unroll
        for (int s = 0; s < 4; ++s) {
            const unsigned short* kp = kbase + (size_t)(c * 64 + s * 16 + m_) * 64;
            short8 B0 = *(const short8*)(kp + quad * 8);
            short8 B1 = *(const short8*)(kp + 32 + quad * 8);
            floatx4 Cv = {0.f, 0.f, 0.f, 0.f};
            Cv = __builtin_amdgcn_mfma_f32_16x16x32_bf16(Aq0, B0, Cv, 0, 0, 0);
            Cv = __builtin_amdgcn_mfma_f32_16x16x32_bf16(Aq1, B1, Cv, 0, 0, 0);
            int colbit = s * 16 + m_;
#pragma unroll
            for (int r = 0; r < 4; ++r) {
                float sval = ((mk[r] >> colbit) & 1ull) ? Cv[r] * ss : -1e9f;
                float p = __expf(sval - mrow[r]) * rlr[r];   // round-3 op order
                float lv = fminf(rintf(p * inv_sa), 127.f);
                plw[(quad * 4 + r) * 68 + colbit] = bf16_exact(lv);
            }
        }
        __asm__ volatile("s_waitcnt lgkmcnt(0)" ::: "memory");
        short8 Ap0 = *(const short8*)&pl[w][ci & 1][m_][quad * 8];
        short8 Ap1 = *(const short8*)&pl[w][ci & 1][m_][32 + quad * 8];
#pragma unroll
        for (int dt = 0; dt < 4; ++dt) {
            acc[dt] = __builtin_amdgcn_mfma_f32_16x16x32_bf16(Ap0, Vb0[dt], acc[dt], 0, 0, 0);
            acc[dt] = __builtin_amdgcn_mfma_f32_16x16x32_bf16(Ap1, Vb1[dt], acc[dt], 0, 0, 0);
        }
        // coalesced attn write: 4 x (b64 LDS read -> float4 store, 256B rows)
#pragma unroll
        for (int it = 0; it < 4; ++it) {
            int rrow = it * 4 + quad, col = m_ * 4;
            uint2 pk = *(const uint2*)&pl[w][ci & 1][rrow][col];
            float4 av;
            av.x = bf16_to_f((unsigned short)(pk.x & 0xffff)) * sa;
            av.y = bf16_to_f((unsigned short)(pk.x >> 16)) * sa;
            av.z = bf16_to_f((unsigned short)(pk.y & 0xffff)) * sa;
            av.w = bf16_to_f((unsigned short)(pk.y >> 16)) * sa;
            *(float4*)(attn_b + (((size_t)(rowbase + rrow)) << 10) + c * 64 + col) = av;
        }
    }
#pragma unroll
    for (int dt = 0; dt < 4; ++dt)
#pragma unroll
        for (int r = 0; r < 4; ++r) {
            int n = rowbase + quad * 4 + r;
            int d = dt * 16 + m_;
            atomicAdd(&out[(size_t)(b * 1024 + n) * 512 + h * 64 + d], acc[dt][r] * sa);
        }
}

// ---------------------------------------------------------------------------
extern "C" void kernel_launch(void* const* d_in, const int* in_sizes, int n_in,
                              void* d_out, int out_size, void* d_ws, size_t ws_size,
                              hipStream_t stream)
{
    (void)in_sizes; (void)n_in; (void)out_size; (void)ws_size;
    const float* x   = (const float*)d_in[0];
    const int*   adj = (const int*)d_in[1];
    const float* W_q = (const float*)d_in[2];
    const float* A_q = (const float*)d_in[3];
    const float* B_q = (const float*)d_in[4];
    const float* m_q = (const float*)d_in[5];
    const float* W_k = (const float*)d_in[6];
    const float* A_k = (const float*)d_in[7];
    const float* B_k = (const float*)d_in[8];
    const float* m_k = (const float*)d_in[9];
    const float* W_v = (const float*)d_in[10];
    const float* A_v = (const float*)d_in[11];
    const float* B_v = (const float*)d_in[12];
    const float* m_v = (const float*)d_in[13];

    char* ws = (char*)d_ws;
    float* wpT          = (float*)(ws + OB_WPT);
    float* xT           = (float*)(ws + OB_XT);
    float* qraw         = (float*)(ws + OB_QRAW);
    float* kraw         = (float*)(ws + OB_KRAW);
    float* vraw         = (float*)(ws + OB_VRAW);
    unsigned short* qlv = (unsigned short*)(ws + OB_QLV);   // overlays vraw
    unsigned short* klv = (unsigned short*)(ws + OB_KLV);   // overlays vraw
    unsigned short* vt  = (unsigned short*)(ws + OB_VT);    // overlays xT
    float2* rowstats    = (float2*)(ws + OB_RS);
    float2* psums       = (float2*)(ws + OB_PS);            // overlays qraw
    unsigned long long* bmask = (unsigned long long*)(ws + OB_BM);
    unsigned int* amax  = (unsigned int*)(ws + OB_AMAX);

    float* out_base  = (float*)d_out;          // (b, n, 512)
    float* attn_base = out_base + 4194304;     // (b, h, n, m)

    hipMemsetAsync(amax, 0, 16, stream);
    hipMemsetAsync(out_base, 0, 16777216, stream);   // out accumulated via atomics

    adj_bits_k<<<32768, 256, 0, stream>>>(adj, bmask);
    transp_k<<<dim3(8, 128), 256, 0, stream>>>(x, xT, 8192, 512);   // x^T

    build_wp3_k<<<dim3(512, 3), 256, 0, stream>>>(W_q, A_q, B_q, m_q,
                                                  W_k, A_k, B_k, m_k,
                                                  W_v, A_v, B_v, m_v, wpT);
    proj_gemm_k<<<dim3(64, 12), 256, 0, stream>>>(xT, wpT, qraw, kraw, vraw, amax);
    // vtrans BEFORE quant2: qlv/klv overlay vraw, which dies here
    vtrans_k<<<dim3(16, 64), 256, 0, stream>>>(vraw, vt);
    quant2_k<<<dim3(4096, 2), 256, 0, stream>>>(qraw, kraw, amax, qlv, klv);

    attn_stats_k<<<dim3(16, 64, 4), 256, 0, stream>>>(qlv, klv, bmask, amax, psums);
    stats_merge_k<<<256, 256, 0, stream>>>(psums, rowstats, amax + 2);
    attn_out_k<<<dim3(16, 64, 2), 256, 0, stream>>>(qlv, klv, vt, bmask, amax,
                                                    rowstats, attn_base, out_base);
}